// Round 6
// baseline (71.820 us; speedup 1.0000x reference)
//
#include <hip/hip_runtime.h>
#include <hip/hip_bf16.h>

#define TSEQ 256
#define NBATCH 2
#define NAG 8
#define NH 8
#define HD 64
#define EE 512
#define WHALF 16
#define WW 33
#define WN 264   // WW*NAG

typedef __attribute__((ext_vector_type(8))) short short8;
typedef __attribute__((ext_vector_type(4))) short short4v;
typedef __attribute__((ext_vector_type(4))) float f32x4;

static __device__ __forceinline__ unsigned short f2bf(float f) {
    unsigned int u = __float_as_uint(f);
    unsigned int r = (u + 0x7FFFu + ((u >> 16) & 1u)) >> 16;
    return (unsigned short)r;
}

// ---------------- fused QKV projection GEMM (bf16 MFMA) -----------------
// BM=128, BN=128, BK=64, 4 waves (2x2, 64x64 each). z picks {q,k,v}.
// z==2 (v) writes TRANSPOSED vt[b][h][d][key=t*8+m] for attn PV B-fragments.
__global__ __launch_bounds__(256)
void proj_mfma_kernel(const float* __restrict__ xq, const float* __restrict__ xk,
                      const float* __restrict__ xv,
                      const float* __restrict__ Wq, const float* __restrict__ Wk,
                      const float* __restrict__ Wv,
                      const float* __restrict__ bq, const float* __restrict__ bk,
                      const float* __restrict__ bv,
                      unsigned short* __restrict__ oq, unsigned short* __restrict__ ok,
                      unsigned short* __restrict__ vt)
{
    __shared__ char As[128 * 128];   // 128 rows x 64 bf16 (swizzled)
    __shared__ char Bs[128 * 128];

    const float* x; const float* W; const float* bias; float scale;
    const int z = blockIdx.z;
    if (z == 0)      { x = xq; W = Wq; bias = bq; scale = 0.125f; }
    else if (z == 1) { x = xk; W = Wk; bias = bk; scale = 1.0f; }
    else             { x = xv; W = Wv; bias = bv; scale = 1.0f; }

    const int tid  = threadIdx.x;
    const int lane = tid & 63;
    const int wid  = tid >> 6;
    const int i0 = blockIdx.x * 128;
    const int f0 = blockIdx.y * 128;
    const int wr = wid >> 1, wc = wid & 1;

    f32x4 acc[4][4];
    #pragma unroll
    for (int m = 0; m < 4; ++m)
        #pragma unroll
        for (int n = 0; n < 4; ++n)
            acc[m][n] = (f32x4){0.f, 0.f, 0.f, 0.f};

    for (int k0 = 0; k0 < EE; k0 += 64) {
        #pragma unroll
        for (int it = 0; it < 8; ++it) {
            const int tt  = tid + it * 256;        // 0..2047
            const int row = tt >> 4, f4 = tt & 15;
            float4 v4 = *reinterpret_cast<const float4*>(x + (size_t)(i0 + row) * EE + k0 + f4 * 4);
            short4v s;
            s[0] = (short)f2bf(v4.x); s[1] = (short)f2bf(v4.y);
            s[2] = (short)f2bf(v4.z); s[3] = (short)f2bf(v4.w);
            *(short4v*)(As + row * 128 + ((f4 * 8) ^ ((row & 7) << 4))) = s;
        }
        #pragma unroll
        for (int it = 0; it < 8; ++it) {
            const int tt  = tid + it * 256;
            const int row = tt >> 4, f4 = tt & 15;
            float4 v4 = *reinterpret_cast<const float4*>(W + (size_t)(f0 + row) * EE + k0 + f4 * 4);
            short4v s;
            s[0] = (short)f2bf(v4.x); s[1] = (short)f2bf(v4.y);
            s[2] = (short)f2bf(v4.z); s[3] = (short)f2bf(v4.w);
            *(short4v*)(Bs + row * 128 + ((f4 * 8) ^ ((row & 7) << 4))) = s;
        }
        __syncthreads();

        #pragma unroll
        for (int ks = 0; ks < 2; ++ks) {
            short8 a[4], b[4];
            #pragma unroll
            for (int m = 0; m < 4; ++m) {
                const int row = wr * 64 + m * 16 + (lane & 15);
                a[m] = *(short8*)(As + row * 128 +
                                  ((ks * 64 + (lane >> 4) * 16) ^ ((row & 7) << 4)));
            }
            #pragma unroll
            for (int n = 0; n < 4; ++n) {
                const int row = wc * 64 + n * 16 + (lane & 15);
                b[n] = *(short8*)(Bs + row * 128 +
                                  ((ks * 64 + (lane >> 4) * 16) ^ ((row & 7) << 4)));
            }
            #pragma unroll
            for (int m = 0; m < 4; ++m)
                #pragma unroll
                for (int n = 0; n < 4; ++n)
                    acc[m][n] = __builtin_amdgcn_mfma_f32_16x16x32_bf16(a[m], b[n], acc[m][n], 0, 0, 0);
        }
        __syncthreads();
    }

    if (z < 2) {
        unsigned short* o = (z == 0) ? oq : ok;
        #pragma unroll
        for (int n = 0; n < 4; ++n) {
            const int col = f0 + wc * 64 + n * 16 + (lane & 15);
            const float bb = bias[col];
            #pragma unroll
            for (int m = 0; m < 4; ++m)
                #pragma unroll
                for (int rg = 0; rg < 4; ++rg) {
                    const int row = i0 + wr * 64 + m * 16 + (lane >> 4) * 4 + rg;
                    o[(size_t)row * EE + col] = f2bf((acc[m][n][rg] + bb) * scale);
                }
        }
    } else {
        // transposed store: vt[((b*8+h)*64+d)*2048 + (t*8+m)]
        #pragma unroll
        for (int n = 0; n < 4; ++n) {
            const int col = f0 + wc * 64 + n * 16 + (lane & 15);
            const int h = col >> 6, d = col & 63;
            const float bb = bias[col];
            #pragma unroll
            for (int m = 0; m < 4; ++m) {
                const int ibase = i0 + wr * 64 + m * 16 + (lane >> 4) * 4;
                const int bb_ = ibase >> 11;          // batch
                const int key = ibase & 2047;
                ushort4 s4;
                s4.x = f2bf(acc[m][n][0] + bb);
                s4.y = f2bf(acc[m][n][1] + bb);
                s4.z = f2bf(acc[m][n][2] + bb);
                s4.w = f2bf(acc[m][n][3] + bb);
                *(ushort4*)(vt + ((size_t)(bb_ * 8 + h) * 64 + d) * 2048 + key) = s4;
            }
        }
    }
}

// ---------------- fused all-heads windowed attention -----------------
// Block = (b, t-pair). 512 threads = 8 waves; wave w owns head h = w.
// P in LDS: [h][16 rows][292 words] fp32 (bf16 alias in-place for PV).
// attn written block-cooperatively: contiguous 135 KB per block, float4 coalesced.
#define PSTR 292                       // words per P row
#define HSTR 4680                      // words per head buffer (16*292 + 8 pad)
#define KM_OFF  149760                 // 8*4680*4 bytes of P
#define INV_OFF 150048                 // km 288B
#define SMEM2_BYTES 150592             // + 128 floats inv + pad

__global__ __launch_bounds__(512, 1)
void attn_fused_kernel(const unsigned short* __restrict__ qb,
                       const unsigned short* __restrict__ kb,
                       const unsigned short* __restrict__ vt,
                       const unsigned char* __restrict__ kpm,
                       float* __restrict__ out,
                       float* __restrict__ attn)
{
    extern __shared__ char smem[];
    float* P    = (float*)smem;
    char*  km   = smem + KM_OFF;
    float* invs = (float*)(smem + INV_OFF);

    const int bid = blockIdx.x;
    const int b   = bid & 1;
    const int tp  = bid >> 1;
    const int t0  = tp * 2;
    const int j0  = t0 - WHALF;            // 36 j's -> 288 local keys
    const int tid = threadIdx.x;
    const int lane = tid & 63;
    const int h    = tid >> 6;             // wave id == head

    // ---- key-valid mask ----
    if (tid < 288) {
        const int c = tid, j = j0 + (c >> 3), m = c & 7;
        km[c] = (j >= 0 && j < TSEQ && kpm[(b * TSEQ + j) * NAG + m] == 0) ? 1 : 0;
    }

    // ---- QK^T per wave: D[16 x 288] from global fragments ----
    {
        const int r = lane & 15;
        const int t = t0 + (r >> 3), n = r & 7;
        const unsigned short* qbase = qb + ((size_t)(b * TSEQ + t) * NAG + n) * EE + h * HD;
        short8 aq0 = *(const short8*)(qbase + (lane >> 4) * 8);
        short8 aq1 = *(const short8*)(qbase + 32 + (lane >> 4) * 8);
        float* Ph = P + h * HSTR;

        #pragma unroll
        for (int g = 0; g < 2; ++g) {
            f32x4 acc[9];
            #pragma unroll
            for (int f = 0; f < 9; ++f) acc[f] = (f32x4){0.f, 0.f, 0.f, 0.f};
            #pragma unroll
            for (int f = 0; f < 9; ++f) {
                const int c = (g * 9 + f) * 16 + (lane & 15);
                int j = j0 + (c >> 3);
                j = (j < 0) ? 0 : ((j > TSEQ - 1) ? TSEQ - 1 : j);
                const int m = c & 7;
                const unsigned short* kbase = kb + ((size_t)(b * TSEQ + j) * NAG + m) * EE + h * HD;
                acc[f] = __builtin_amdgcn_mfma_f32_16x16x32_bf16(
                    aq0, *(const short8*)(kbase + (lane >> 4) * 8), acc[f], 0, 0, 0);
                acc[f] = __builtin_amdgcn_mfma_f32_16x16x32_bf16(
                    aq1, *(const short8*)(kbase + 32 + (lane >> 4) * 8), acc[f], 0, 0, 0);
            }
            const int r0 = (lane >> 4) * 4;
            #pragma unroll
            for (int f = 0; f < 9; ++f) {
                const int col = (g * 9 + f) * 16 + (lane & 15);
                #pragma unroll
                for (int rg = 0; rg < 4; ++rg)
                    Ph[(r0 + rg) * PSTR + col] = acc[f][rg];
            }
        }
    }
    __syncthreads();

    // ---- softmax per wave: 4 lanes per row, 16 rows ----
    {
        const int r = lane & 15, qq = lane >> 4;
        const int win0 = (r >> 3) * 8;
        float* prow = P + h * HSTR + r * PSTR;
        float mx = -INFINITY;
        #pragma unroll 6
        for (int i = 0; i < 66; ++i) {
            const int c = win0 + qq + 4 * i;
            if (km[c]) mx = fmaxf(mx, prow[c]);
        }
        mx = fmaxf(mx, __shfl_xor(mx, 16));
        mx = fmaxf(mx, __shfl_xor(mx, 32));
        float sum = 0.f;
        #pragma unroll 6
        for (int i = 0; i < 72; ++i) {
            const int c = qq + 4 * i;
            const bool in = (c >= win0) && (c < win0 + WN) && km[c];
            const float p = in ? __expf(prow[c] - mx) : 0.f;
            prow[c] = p;
            sum += p;
        }
        sum += __shfl_xor(sum, 16);
        sum += __shfl_xor(sum, 32);
        if (qq == 0) invs[h * 16 + r] = 1.f / sum;
    }
    __syncthreads();

    // ---- cooperative coalesced attn write: 8448 float4 = 135 KB contiguous ----
    {
        float* abase = attn + (size_t)(b * TSEQ + t0) * (NAG * WN * NH);
        for (int q4 = tid; q4 < 8448; q4 += 512) {
            const int hh  = q4 & 1;
            const int rw  = q4 >> 1;
            const int row = rw / WN;
            const int wm  = rw - row * WN;
            const int c   = (row >> 3) * 8 + wm;
            const int h0  = hh * 4;
            const float* pp = P + h0 * HSTR + row * PSTR + c;
            float4 v;
            v.x = pp[0]        * invs[(h0 + 0) * 16 + row];
            v.y = pp[HSTR]     * invs[(h0 + 1) * 16 + row];
            v.z = pp[2 * HSTR] * invs[(h0 + 2) * 16 + row];
            v.w = pp[3 * HSTR] * invs[(h0 + 3) * 16 + row];
            *(float4*)(abase + (size_t)q4 * 4) = v;
        }
    }
    __syncthreads();

    // ---- in-place bf16 repack (own head), two alias-safe phases ----
    {
        const int r = lane & 15, qq = lane >> 4;
        float* prow = P + h * HSTR + r * PSTR;
        char*  brow = (char*)prow;
        const float inv = invs[h * 16 + r];
        float tmp[36];
        // phase 1: fp32 cols [0,144) -> bf16 bytes [0,288)
        #pragma unroll
        for (int i = 0; i < 36; ++i) tmp[i] = prow[qq * 36 + i];
        __builtin_amdgcn_sched_barrier(0);
        asm volatile("s_waitcnt lgkmcnt(0)" ::: "memory");
        __builtin_amdgcn_sched_barrier(0);
        #pragma unroll
        for (int i = 0; i < 36; ++i)
            *(unsigned short*)(brow + 2 * (qq * 36 + i)) = f2bf(tmp[i] * inv);
        __builtin_amdgcn_sched_barrier(0);
        asm volatile("s_waitcnt lgkmcnt(0)" ::: "memory");
        __builtin_amdgcn_sched_barrier(0);
        // phase 2: fp32 cols [144,288) -> bf16 bytes [288,576)
        #pragma unroll
        for (int i = 0; i < 36; ++i) tmp[i] = prow[144 + qq * 36 + i];
        __builtin_amdgcn_sched_barrier(0);
        asm volatile("s_waitcnt lgkmcnt(0)" ::: "memory");
        __builtin_amdgcn_sched_barrier(0);
        #pragma unroll
        for (int i = 0; i < 36; ++i)
            *(unsigned short*)(brow + 2 * (144 + qq * 36 + i)) = f2bf(tmp[i] * inv);
        __builtin_amdgcn_sched_barrier(0);
        asm volatile("s_waitcnt lgkmcnt(0)" ::: "memory");
        __builtin_amdgcn_sched_barrier(0);
    }

    // ---- PV per wave: D[16 x 64], A = P bf16 (LDS), B = vt (global) ----
    {
        const int key0 = j0 * 8;
        const unsigned short* vth = vt + ((size_t)(b * 8 + h) * 64) * 2048;
        const char* abase2 = smem + h * (HSTR * 4);
        f32x4 acc[4];
        #pragma unroll
        for (int df = 0; df < 4; ++df) acc[df] = (f32x4){0.f, 0.f, 0.f, 0.f};
        #pragma unroll
        for (int ms = 0; ms < 9; ++ms) {
            short8 afr = *(short8*)(abase2 + (lane & 15) * (PSTR * 4) + ms * 64 + (lane >> 4) * 16);
            int kc = key0 + ms * 32 + (lane >> 4) * 8;
            kc = (kc < 0) ? 0 : ((kc > 2040) ? 2040 : kc);
            #pragma unroll
            for (int df = 0; df < 4; ++df) {
                const int d = df * 16 + (lane & 15);
                short8 bfr = *(const short8*)(vth + (size_t)d * 2048 + kc);
                acc[df] = __builtin_amdgcn_mfma_f32_16x16x32_bf16(afr, bfr, acc[df], 0, 0, 0);
            }
        }
        #pragma unroll
        for (int df = 0; df < 4; ++df) {
            const int d = df * 16 + (lane & 15);
            #pragma unroll
            for (int rg = 0; rg < 4; ++rg) {
                const int row = (lane >> 4) * 4 + rg;
                const int t = t0 + (row >> 3), n = row & 7;
                out[((size_t)(b * TSEQ + t) * NAG + n) * EE + h * HD + d] = acc[df][rg];
            }
        }
    }
}

extern "C" void kernel_launch(void* const* d_in, const int* in_sizes, int n_in,
                              void* d_out, int out_size, void* d_ws, size_t ws_size,
                              hipStream_t stream) {
    const float* query = (const float*)d_in[0];
    const float* key   = (const float*)d_in[1];
    const float* value = (const float*)d_in[2];
    const unsigned char* kpm = (const unsigned char*)d_in[3];
    const float* Wq = (const float*)d_in[4];
    const float* bq = (const float*)d_in[5];
    const float* Wk = (const float*)d_in[6];
    const float* bk = (const float*)d_in[7];
    const float* Wv = (const float*)d_in[8];
    const float* bv = (const float*)d_in[9];

    float* out  = (float*)d_out;
    float* attn = out + (size_t)NBATCH * TSEQ * NAG * EE;

    unsigned short* qbf = (unsigned short*)d_ws;               // 4 MB bf16
    unsigned short* kbf = qbf + (size_t)4096 * EE;             // 4 MB
    unsigned short* vtb = kbf + (size_t)4096 * EE;             // 4 MB transposed V

    dim3 gp(32, 4, 3);
    proj_mfma_kernel<<<gp, 256, 0, stream>>>(query, key, value,
                                             Wq, Wk, Wv, bq, bk, bv,
                                             qbf, kbf, vtb);

    (void)hipFuncSetAttribute((const void*)attn_fused_kernel,
                              hipFuncAttributeMaxDynamicSharedMemorySize, SMEM2_BYTES);
    attn_fused_kernel<<<256, 512, SMEM2_BYTES, stream>>>(qbf, kbf, vtb, kpm, out, attn);
}

// Round 7
// 69.731 us; speedup vs baseline: 1.0300x; 1.0300x over previous
//
#include <hip/hip_runtime.h>
#include <hip/hip_bf16.h>

#define TSEQ 256
#define NBATCH 2
#define NAG 8
#define NH 8
#define HD 64
#define EE 512
#define WHALF 16
#define WW 33
#define WN 264   // WW*NAG

typedef __attribute__((ext_vector_type(8))) short short8;
typedef __attribute__((ext_vector_type(4))) short short4v;
typedef __attribute__((ext_vector_type(4))) float f32x4;

static __device__ __forceinline__ unsigned short f2bf(float f) {
    unsigned int u = __float_as_uint(f);
    unsigned int r = (u + 0x7FFFu + ((u >> 16) & 1u)) >> 16;
    return (unsigned short)r;
}

// ---------------- fused QKV projection GEMM (bf16 MFMA) -----------------
// BM=128, BN=128, BK=64, 4 waves (2x2, 64x64 each). z picks {q,k,v}.
// z==2 (v) writes TRANSPOSED vt[b][h][d][key=t*8+m] for attn PV B-fragments.
__global__ __launch_bounds__(256)
void proj_mfma_kernel(const float* __restrict__ xq, const float* __restrict__ xk,
                      const float* __restrict__ xv,
                      const float* __restrict__ Wq, const float* __restrict__ Wk,
                      const float* __restrict__ Wv,
                      const float* __restrict__ bq, const float* __restrict__ bk,
                      const float* __restrict__ bv,
                      unsigned short* __restrict__ oq, unsigned short* __restrict__ ok,
                      unsigned short* __restrict__ vt)
{
    __shared__ char As[128 * 128];   // 128 rows x 64 bf16 (swizzled)
    __shared__ char Bs[128 * 128];

    const float* x; const float* W; const float* bias; float scale;
    const int z = blockIdx.z;
    if (z == 0)      { x = xq; W = Wq; bias = bq; scale = 0.125f; }
    else if (z == 1) { x = xk; W = Wk; bias = bk; scale = 1.0f; }
    else             { x = xv; W = Wv; bias = bv; scale = 1.0f; }

    const int tid  = threadIdx.x;
    const int lane = tid & 63;
    const int wid  = tid >> 6;
    const int i0 = blockIdx.x * 128;
    const int f0 = blockIdx.y * 128;
    const int wr = wid >> 1, wc = wid & 1;

    f32x4 acc[4][4];
    #pragma unroll
    for (int m = 0; m < 4; ++m)
        #pragma unroll
        for (int n = 0; n < 4; ++n)
            acc[m][n] = (f32x4){0.f, 0.f, 0.f, 0.f};

    for (int k0 = 0; k0 < EE; k0 += 64) {
        #pragma unroll
        for (int it = 0; it < 8; ++it) {
            const int tt  = tid + it * 256;        // 0..2047
            const int row = tt >> 4, f4 = tt & 15;
            float4 v4 = *reinterpret_cast<const float4*>(x + (size_t)(i0 + row) * EE + k0 + f4 * 4);
            short4v s;
            s[0] = (short)f2bf(v4.x); s[1] = (short)f2bf(v4.y);
            s[2] = (short)f2bf(v4.z); s[3] = (short)f2bf(v4.w);
            *(short4v*)(As + row * 128 + ((f4 * 8) ^ ((row & 7) << 4))) = s;
        }
        #pragma unroll
        for (int it = 0; it < 8; ++it) {
            const int tt  = tid + it * 256;
            const int row = tt >> 4, f4 = tt & 15;
            float4 v4 = *reinterpret_cast<const float4*>(W + (size_t)(f0 + row) * EE + k0 + f4 * 4);
            short4v s;
            s[0] = (short)f2bf(v4.x); s[1] = (short)f2bf(v4.y);
            s[2] = (short)f2bf(v4.z); s[3] = (short)f2bf(v4.w);
            *(short4v*)(Bs + row * 128 + ((f4 * 8) ^ ((row & 7) << 4))) = s;
        }
        __syncthreads();

        #pragma unroll
        for (int ks = 0; ks < 2; ++ks) {
            short8 a[4], b[4];
            #pragma unroll
            for (int m = 0; m < 4; ++m) {
                const int row = wr * 64 + m * 16 + (lane & 15);
                a[m] = *(short8*)(As + row * 128 +
                                  ((ks * 64 + (lane >> 4) * 16) ^ ((row & 7) << 4)));
            }
            #pragma unroll
            for (int n = 0; n < 4; ++n) {
                const int row = wc * 64 + n * 16 + (lane & 15);
                b[n] = *(short8*)(Bs + row * 128 +
                                  ((ks * 64 + (lane >> 4) * 16) ^ ((row & 7) << 4)));
            }
            #pragma unroll
            for (int m = 0; m < 4; ++m)
                #pragma unroll
                for (int n = 0; n < 4; ++n)
                    acc[m][n] = __builtin_amdgcn_mfma_f32_16x16x32_bf16(a[m], b[n], acc[m][n], 0, 0, 0);
        }
        __syncthreads();
    }

    if (z < 2) {
        unsigned short* o = (z == 0) ? oq : ok;
        #pragma unroll
        for (int n = 0; n < 4; ++n) {
            const int col = f0 + wc * 64 + n * 16 + (lane & 15);
            const float bb = bias[col];
            #pragma unroll
            for (int m = 0; m < 4; ++m)
                #pragma unroll
                for (int rg = 0; rg < 4; ++rg) {
                    const int row = i0 + wr * 64 + m * 16 + (lane >> 4) * 4 + rg;
                    o[(size_t)row * EE + col] = f2bf((acc[m][n][rg] + bb) * scale);
                }
        }
    } else {
        // transposed store: vt[((b*8+h)*64+d)*2048 + (t*8+m)]
        #pragma unroll
        for (int n = 0; n < 4; ++n) {
            const int col = f0 + wc * 64 + n * 16 + (lane & 15);
            const int h = col >> 6, d = col & 63;
            const float bb = bias[col];
            #pragma unroll
            for (int m = 0; m < 4; ++m) {
                const int ibase = i0 + wr * 64 + m * 16 + (lane >> 4) * 4;
                const int bb_ = ibase >> 11;          // batch
                const int key = ibase & 2047;
                ushort4 s4;
                s4.x = f2bf(acc[m][n][0] + bb);
                s4.y = f2bf(acc[m][n][1] + bb);
                s4.z = f2bf(acc[m][n][2] + bb);
                s4.w = f2bf(acc[m][n][3] + bb);
                *(ushort4*)(vt + ((size_t)(bb_ * 8 + h) * 64 + d) * 2048 + key) = s4;
            }
        }
    }
}

// ---------------- fused all-heads windowed attention, single-t blocks --------
// Block = (b, t). 512 threads = 8 waves; wave w owns head h = w.
// P in LDS: [h][8 rows][280 words] fp32, bf16 alias (first 144 words) for PV.
// attn region per block = 16896 floats CONTIGUOUS -> full-line coalesced writes.
#define RS   280                       // fp32 words per P row
#define HB   2248                      // words per head buffer (8*280 + 8 pad)
#define KM_OFF  (8 * HB * 4)           // 71936 : km 264B (+pad)
#define INV_OFF (KM_OFF + 288)         // 72224 : 64 floats
#define SMEM2_BYTES (INV_OFF + 256 + 32)

__global__ __launch_bounds__(512, 4)
void attn_fused_kernel(const unsigned short* __restrict__ qb,
                       const unsigned short* __restrict__ kb,
                       const unsigned short* __restrict__ vt,
                       const unsigned char* __restrict__ kpm,
                       float* __restrict__ out,
                       float* __restrict__ attn)
{
    extern __shared__ char smem[];
    float* P    = (float*)smem;
    char*  km   = smem + KM_OFF;
    float* invs = (float*)(smem + INV_OFF);

    // XCD swizzle: each XCD (bid%8) owns a contiguous (b,t) range -> window
    // K/vt reads of neighboring t hit the same XCD's L2.
    const int bid = blockIdx.x;
    const int lin = (bid & 7) * 64 + (bid >> 3);   // 0..511
    const int b   = lin >> 8;
    const int t   = lin & 255;
    const int j0  = t - WHALF;
    const int key0 = j0 * 8;
    const int tid = threadIdx.x;
    const int lane = tid & 63;
    const int h    = tid >> 6;             // wave id == head

    // ---- key-valid mask (264 local keys) ----
    if (tid < WN) {
        const int j = j0 + (tid >> 3), m = tid & 7;
        km[tid] = (j >= 0 && j < TSEQ && kpm[(b * TSEQ + j) * NAG + m] == 0) ? 1 : 0;
    }

    // ---- QK^T per wave: D[8 real rows x 272 cols] from global fragments ----
    {
        const int n = lane & 7;                       // A rows 8..15 duplicate 0..7
        const unsigned short* qbase = qb + ((size_t)(b * TSEQ + t) * NAG + n) * EE + h * HD;
        short8 aq0 = *(const short8*)(qbase + (lane >> 4) * 8);
        short8 aq1 = *(const short8*)(qbase + 32 + (lane >> 4) * 8);
        float* Ph = P + h * HB;
        const int r0 = (lane >> 4) * 4;

        #pragma unroll
        for (int f = 0; f < 17; ++f) {
            const int c = f * 16 + (lane & 15);       // 0..271
            int j = j0 + (c >> 3);
            j = (j < 0) ? 0 : ((j > TSEQ - 1) ? TSEQ - 1 : j);
            const int m = c & 7;
            const unsigned short* kbase = kb + ((size_t)(b * TSEQ + j) * NAG + m) * EE + h * HD;
            f32x4 a = (f32x4){0.f, 0.f, 0.f, 0.f};
            a = __builtin_amdgcn_mfma_f32_16x16x32_bf16(
                aq0, *(const short8*)(kbase + (lane >> 4) * 8), a, 0, 0, 0);
            a = __builtin_amdgcn_mfma_f32_16x16x32_bf16(
                aq1, *(const short8*)(kbase + 32 + (lane >> 4) * 8), a, 0, 0, 0);
            if (r0 < 8) {                              // rows 0..7 only
                #pragma unroll
                for (int rg = 0; rg < 4; ++rg)
                    Ph[(r0 + rg) * RS + f * 16 + (lane & 15)] = a[rg];
            }
        }
    }
    __syncthreads();

    // ---- softmax per wave: 8 lanes per row, 8 rows, 264 cols ----
    {
        const int r = lane & 7, sub = lane >> 3;
        float* prow = P + h * HB + r * RS;
        float mx = -INFINITY;
        #pragma unroll 3
        for (int i = 0; i < 33; ++i) {
            const int c = sub + 8 * i;                 // < 264
            if (km[c]) mx = fmaxf(mx, prow[c]);
        }
        mx = fmaxf(mx, __shfl_xor(mx, 8));
        mx = fmaxf(mx, __shfl_xor(mx, 16));
        mx = fmaxf(mx, __shfl_xor(mx, 32));
        float sum = 0.f;
        #pragma unroll 3
        for (int i = 0; i < 33; ++i) {
            const int c = sub + 8 * i;
            const float p = km[c] ? __expf(prow[c] - mx) : 0.f;
            prow[c] = p;
            sum += p;
        }
        sum += __shfl_xor(sum, 8);
        sum += __shfl_xor(sum, 16);
        sum += __shfl_xor(sum, 32);
        if (sub == 0) invs[h * 8 + r] = 1.f / sum;
    }
    __syncthreads();

    // ---- cooperative coalesced attn write: 4224 float4 = 67.6 KB contiguous ----
    {
        float* abase = attn + (size_t)(b * TSEQ + t) * (NAG * WN * NH);
        #pragma unroll 3
        for (int q4 = tid; q4 < 4224; q4 += 512) {
            const int hh = q4 & 1;
            const int rw = q4 >> 1;                    // n*264 + wm
            const int n  = rw / WN;
            const int wm = rw - n * WN;
            const int h0 = hh * 4;
            const float* pp = P + h0 * HB + n * RS + wm;
            float4 v;
            v.x = pp[0]      * invs[(h0 + 0) * 8 + n];
            v.y = pp[HB]     * invs[(h0 + 1) * 8 + n];
            v.z = pp[2 * HB] * invs[(h0 + 2) * 8 + n];
            v.w = pp[3 * HB] * invs[(h0 + 3) * 8 + n];
            *(float4*)(abase + (size_t)q4 * 4) = v;
        }
    }
    __syncthreads();

    // ---- in-place bf16 repack (own head), two alias-safe phases ----
    {
        const int r = lane & 7, sub = lane >> 3;
        float* prow = P + h * HB + r * RS;
        char*  brow = (char*)prow;
        const float inv = invs[h * 8 + r];
        float tmp[18];
        // phase 1: fp32 cols [0,144) -> bf16 bytes [0,288) (= fp32 words 0..71)
        #pragma unroll
        for (int i = 0; i < 18; ++i) tmp[i] = prow[sub + 8 * i];
        __builtin_amdgcn_sched_barrier(0);
        asm volatile("s_waitcnt lgkmcnt(0)" ::: "memory");
        __builtin_amdgcn_sched_barrier(0);
        #pragma unroll
        for (int i = 0; i < 18; ++i)
            *(unsigned short*)(brow + 2 * (sub + 8 * i)) = f2bf(tmp[i] * inv);
        __builtin_amdgcn_sched_barrier(0);
        asm volatile("s_waitcnt lgkmcnt(0)" ::: "memory");
        __builtin_amdgcn_sched_barrier(0);
        // phase 2: fp32 cols [144,288) -> bf16 bytes [288,576) (= words 72..143)
        #pragma unroll
        for (int i = 0; i < 18; ++i) {
            const int c = 144 + sub + 8 * i;
            tmp[i] = (c < WN) ? prow[c] : 0.f;
        }
        __builtin_amdgcn_sched_barrier(0);
        asm volatile("s_waitcnt lgkmcnt(0)" ::: "memory");
        __builtin_amdgcn_sched_barrier(0);
        #pragma unroll
        for (int i = 0; i < 18; ++i) {
            const int c = 144 + sub + 8 * i;
            *(unsigned short*)(brow + 2 * c) = f2bf(tmp[i] * inv);
        }
        __builtin_amdgcn_sched_barrier(0);
        asm volatile("s_waitcnt lgkmcnt(0)" ::: "memory");
        __builtin_amdgcn_sched_barrier(0);
    }

    // ---- PV per wave: D[8 real rows x 64], A = P bf16 (LDS), B = vt (global) ----
    {
        const unsigned short* vth = vt + ((size_t)(b * 8 + h) * 64) * 2048;
        const char* arow = smem + (size_t)h * (HB * 4) + (lane & 7) * (RS * 4);
        f32x4 acc[4];
        #pragma unroll
        for (int df = 0; df < 4; ++df) acc[df] = (f32x4){0.f, 0.f, 0.f, 0.f};
        #pragma unroll
        for (int ms = 0; ms < 9; ++ms) {
            short8 afr = *(short8*)(arow + ms * 64 + (lane >> 4) * 16);
            int kc = key0 + ms * 32 + (lane >> 4) * 8;
            kc = (kc < 0) ? 0 : ((kc > 2040) ? 2040 : kc);
            #pragma unroll
            for (int df = 0; df < 4; ++df) {
                const int d = df * 16 + (lane & 15);
                short8 bfr = *(const short8*)(vth + (size_t)d * 2048 + kc);
                acc[df] = __builtin_amdgcn_mfma_f32_16x16x32_bf16(afr, bfr, acc[df], 0, 0, 0);
            }
        }
        const int r0 = (lane >> 4) * 4;
        if (r0 < 8) {
            #pragma unroll
            for (int df = 0; df < 4; ++df) {
                const int d = df * 16 + (lane & 15);
                #pragma unroll
                for (int rg = 0; rg < 4; ++rg) {
                    const int n = r0 + rg;             // row == agent n (single t)
                    out[((size_t)(b * TSEQ + t) * NAG + n) * EE + h * HD + d] = acc[df][rg];
                }
            }
        }
    }
}

extern "C" void kernel_launch(void* const* d_in, const int* in_sizes, int n_in,
                              void* d_out, int out_size, void* d_ws, size_t ws_size,
                              hipStream_t stream) {
    const float* query = (const float*)d_in[0];
    const float* key   = (const float*)d_in[1];
    const float* value = (const float*)d_in[2];
    const unsigned char* kpm = (const unsigned char*)d_in[3];
    const float* Wq = (const float*)d_in[4];
    const float* bq = (const float*)d_in[5];
    const float* Wk = (const float*)d_in[6];
    const float* bk = (const float*)d_in[7];
    const float* Wv = (const float*)d_in[8];
    const float* bv = (const float*)d_in[9];

    float* out  = (float*)d_out;
    float* attn = out + (size_t)NBATCH * TSEQ * NAG * EE;

    unsigned short* qbf = (unsigned short*)d_ws;               // 4 MB bf16
    unsigned short* kbf = qbf + (size_t)4096 * EE;             // 4 MB
    unsigned short* vtb = kbf + (size_t)4096 * EE;             // 4 MB transposed V

    dim3 gp(32, 4, 3);
    proj_mfma_kernel<<<gp, 256, 0, stream>>>(query, key, value,
                                             Wq, Wk, Wv, bq, bk, bv,
                                             qbf, kbf, vtb);

    (void)hipFuncSetAttribute((const void*)attn_fused_kernel,
                              hipFuncAttributeMaxDynamicSharedMemorySize, SMEM2_BYTES);
    attn_fused_kernel<<<512, 512, SMEM2_BYTES, stream>>>(qbf, kbf, vtb, kpm, out, attn);
}

// Round 9
// 64.641 us; speedup vs baseline: 1.1111x; 1.0787x over previous
//
#include <hip/hip_runtime.h>
#include <hip/hip_bf16.h>

#define TSEQ 256
#define NBATCH 2
#define NAG 8
#define NH 8
#define HD 64
#define EE 512
#define WHALF 16
#define WW 33
#define WN 264   // WW*NAG

typedef __attribute__((ext_vector_type(8))) short short8;
typedef __attribute__((ext_vector_type(4))) short short4v;
typedef __attribute__((ext_vector_type(4))) float f32x4;

static __device__ __forceinline__ unsigned short f2bf(float f) {
    unsigned int u = __float_as_uint(f);
    unsigned int r = (u + 0x7FFFu + ((u >> 16) & 1u)) >> 16;
    return (unsigned short)r;
}

// ---------------- fused QKV projection GEMM (bf16 MFMA) -----------------
// BM=128, BN=128, BK=64, 4 waves (2x2, 64x64 each). z picks {q,k,v}.
// z==2 (v) writes TRANSPOSED vt[b][h][d][key=t*8+m] for attn PV B-fragments.
__global__ __launch_bounds__(256)
void proj_mfma_kernel(const float* __restrict__ xq, const float* __restrict__ xk,
                      const float* __restrict__ xv,
                      const float* __restrict__ Wq, const float* __restrict__ Wk,
                      const float* __restrict__ Wv,
                      const float* __restrict__ bq, const float* __restrict__ bk,
                      const float* __restrict__ bv,
                      unsigned short* __restrict__ oq, unsigned short* __restrict__ ok,
                      unsigned short* __restrict__ vt)
{
    __shared__ char As[128 * 128];   // 128 rows x 64 bf16 (swizzled)
    __shared__ char Bs[128 * 128];

    const float* x; const float* W; const float* bias; float scale;
    const int z = blockIdx.z;
    if (z == 0)      { x = xq; W = Wq; bias = bq; scale = 0.125f; }
    else if (z == 1) { x = xk; W = Wk; bias = bk; scale = 1.0f; }
    else             { x = xv; W = Wv; bias = bv; scale = 1.0f; }

    const int tid  = threadIdx.x;
    const int lane = tid & 63;
    const int wid  = tid >> 6;
    const int i0 = blockIdx.x * 128;
    const int f0 = blockIdx.y * 128;
    const int wr = wid >> 1, wc = wid & 1;

    f32x4 acc[4][4];
    #pragma unroll
    for (int m = 0; m < 4; ++m)
        #pragma unroll
        for (int n = 0; n < 4; ++n)
            acc[m][n] = (f32x4){0.f, 0.f, 0.f, 0.f};

    for (int k0 = 0; k0 < EE; k0 += 64) {
        #pragma unroll
        for (int it = 0; it < 8; ++it) {
            const int tt  = tid + it * 256;        // 0..2047
            const int row = tt >> 4, f4 = tt & 15;
            float4 v4 = *reinterpret_cast<const float4*>(x + (size_t)(i0 + row) * EE + k0 + f4 * 4);
            short4v s;
            s[0] = (short)f2bf(v4.x); s[1] = (short)f2bf(v4.y);
            s[2] = (short)f2bf(v4.z); s[3] = (short)f2bf(v4.w);
            *(short4v*)(As + row * 128 + ((f4 * 8) ^ ((row & 7) << 4))) = s;
        }
        #pragma unroll
        for (int it = 0; it < 8; ++it) {
            const int tt  = tid + it * 256;
            const int row = tt >> 4, f4 = tt & 15;
            float4 v4 = *reinterpret_cast<const float4*>(W + (size_t)(f0 + row) * EE + k0 + f4 * 4);
            short4v s;
            s[0] = (short)f2bf(v4.x); s[1] = (short)f2bf(v4.y);
            s[2] = (short)f2bf(v4.z); s[3] = (short)f2bf(v4.w);
            *(short4v*)(Bs + row * 128 + ((f4 * 8) ^ ((row & 7) << 4))) = s;
        }
        __syncthreads();

        #pragma unroll
        for (int ks = 0; ks < 2; ++ks) {
            short8 a[4], b[4];
            #pragma unroll
            for (int m = 0; m < 4; ++m) {
                const int row = wr * 64 + m * 16 + (lane & 15);
                a[m] = *(short8*)(As + row * 128 +
                                  ((ks * 64 + (lane >> 4) * 16) ^ ((row & 7) << 4)));
            }
            #pragma unroll
            for (int n = 0; n < 4; ++n) {
                const int row = wc * 64 + n * 16 + (lane & 15);
                b[n] = *(short8*)(Bs + row * 128 +
                                  ((ks * 64 + (lane >> 4) * 16) ^ ((row & 7) << 4)));
            }
            #pragma unroll
            for (int m = 0; m < 4; ++m)
                #pragma unroll
                for (int n = 0; n < 4; ++n)
                    acc[m][n] = __builtin_amdgcn_mfma_f32_16x16x32_bf16(a[m], b[n], acc[m][n], 0, 0, 0);
        }
        __syncthreads();
    }

    if (z < 2) {
        unsigned short* o = (z == 0) ? oq : ok;
        #pragma unroll
        for (int n = 0; n < 4; ++n) {
            const int col = f0 + wc * 64 + n * 16 + (lane & 15);
            const float bb = bias[col];
            #pragma unroll
            for (int m = 0; m < 4; ++m)
                #pragma unroll
                for (int rg = 0; rg < 4; ++rg) {
                    const int row = i0 + wr * 64 + m * 16 + (lane >> 4) * 4 + rg;
                    o[(size_t)row * EE + col] = f2bf((acc[m][n][rg] + bb) * scale);
                }
        }
    } else {
        // transposed store: vt[((b*8+h)*64+d)*2048 + (t*8+m)]
        #pragma unroll
        for (int n = 0; n < 4; ++n) {
            const int col = f0 + wc * 64 + n * 16 + (lane & 15);
            const int h = col >> 6, d = col & 63;
            const float bb = bias[col];
            #pragma unroll
            for (int m = 0; m < 4; ++m) {
                const int ibase = i0 + wr * 64 + m * 16 + (lane >> 4) * 4;
                const int bb_ = ibase >> 11;          // batch
                const int key = ibase & 2047;
                ushort4 s4;
                s4.x = f2bf(acc[m][n][0] + bb);
                s4.y = f2bf(acc[m][n][1] + bb);
                s4.z = f2bf(acc[m][n][2] + bb);
                s4.w = f2bf(acc[m][n][3] + bb);
                *(ushort4*)(vt + ((size_t)(bb_ * 8 + h) * 64 + d) * 2048 + key) = s4;
            }
        }
    }
}

// ---------------- fused all-heads windowed attention, single-t blocks --------
// Block = (b, t). 512 threads = 8 waves; wave w owns head h = w.
// Deep-prefetched global fragment reads (L3-latency hiding); softmax values
// held in registers; bf16 P written once covering cols [0,288) (PV reads 288).
#define RS   280                       // fp32 words per P row
#define HB   2248                      // words per head buffer (8*280 + 8 pad)
#define KM_OFF  (8 * HB * 4)           // 71936 : km 264B (+pad)
#define INV_OFF (KM_OFF + 288)         // 72224 : 64 floats
#define SMEM2_BYTES (INV_OFF + 256 + 32)

__global__ __launch_bounds__(512, 4)
void attn_fused_kernel(const unsigned short* __restrict__ qb,
                       const unsigned short* __restrict__ kb,
                       const unsigned short* __restrict__ vt,
                       const unsigned char* __restrict__ kpm,
                       float* __restrict__ out,
                       float* __restrict__ attn)
{
    extern __shared__ char smem[];
    float* P    = (float*)smem;
    char*  km   = smem + KM_OFF;
    float* invs = (float*)(smem + INV_OFF);

    // XCD swizzle: each XCD (bid%8) owns a contiguous (b,t) range.
    const int bid = blockIdx.x;
    const int lin = (bid & 7) * 64 + (bid >> 3);   // 0..511
    const int b   = lin >> 8;
    const int t   = lin & 255;
    const int j0  = t - WHALF;
    const int key0 = j0 * 8;
    const int tid = threadIdx.x;
    const int lane = tid & 63;
    const int h    = tid >> 6;             // wave id == head

    // ---- key-valid mask (264 local keys) ----
    if (tid < WN) {
        const int j = j0 + (tid >> 3), m = tid & 7;
        km[tid] = (j >= 0 && j < TSEQ && kpm[(b * TSEQ + j) * NAG + m] == 0) ? 1 : 0;
    }

    // ---- QK^T per wave: D[8 real rows x 272 cols], depth-6 ring prefetch ----
    {
        const int n = lane & 7;                       // A rows 8..15 duplicate 0..7
        const unsigned short* qbase = qb + ((size_t)(b * TSEQ + t) * NAG + n) * EE + h * HD;
        short8 aq0 = *(const short8*)(qbase + (lane >> 4) * 8);
        short8 aq1 = *(const short8*)(qbase + 32 + (lane >> 4) * 8);
        float* Ph = P + h * HB;
        const int r0 = (lane >> 4) * 4;
        const int cl = lane & 15;

        auto kaddr = [&](int f) -> const unsigned short* {
            const int c = f * 16 + cl;
            int j = j0 + (c >> 3);
            j = (j < 0) ? 0 : ((j > TSEQ - 1) ? TSEQ - 1 : j);
            return kb + ((size_t)(b * TSEQ + j) * NAG + (c & 7)) * EE + h * HD + (lane >> 4) * 8;
        };

        short8 ka[6], kb2[6];
        #pragma unroll
        for (int f = 0; f < 6; ++f) {
            const unsigned short* p = kaddr(f);
            ka[f]  = *(const short8*)p;
            kb2[f] = *(const short8*)(p + 32);
        }
        #pragma unroll
        for (int f = 0; f < 17; ++f) {
            f32x4 a = (f32x4){0.f, 0.f, 0.f, 0.f};
            a = __builtin_amdgcn_mfma_f32_16x16x32_bf16(aq0, ka[f % 6],  a, 0, 0, 0);
            a = __builtin_amdgcn_mfma_f32_16x16x32_bf16(aq1, kb2[f % 6], a, 0, 0, 0);
            if (f + 6 < 17) {
                const unsigned short* p = kaddr(f + 6);
                ka[f % 6]  = *(const short8*)p;
                kb2[f % 6] = *(const short8*)(p + 32);
            }
            if (r0 < 8) {
                #pragma unroll
                for (int rg = 0; rg < 4; ++rg)
                    Ph[(r0 + rg) * RS + f * 16 + cl] = a[rg];
            }
        }
    }
    __syncthreads();

    // ---- softmax per wave: 8 lanes/row, values kept in registers ----
    float vals[36];                      // 36 cols/lane -> covers bf16 cols [0,288)
    float invv;
    {
        const int r = lane & 7, sub = lane >> 3;
        float* prow = P + h * HB + r * RS;
        float mx = -INFINITY;
        #pragma unroll
        for (int i = 0; i < 33; ++i) {
            const int c = sub + 8 * i;                 // < 264
            const float lv = prow[c];
            vals[i] = km[c] ? lv : -INFINITY;
            mx = fmaxf(mx, vals[i]);
        }
        mx = fmaxf(mx, __shfl_xor(mx, 8));
        mx = fmaxf(mx, __shfl_xor(mx, 16));
        mx = fmaxf(mx, __shfl_xor(mx, 32));
        float sum = 0.f;
        #pragma unroll
        for (int i = 0; i < 33; ++i) {
            const float p = (vals[i] == -INFINITY) ? 0.f : __expf(vals[i] - mx);
            vals[i] = p;
            prow[sub + 8 * i] = p;                     // fp32 for cross-head attn write
            sum += p;
        }
        vals[33] = 0.f; vals[34] = 0.f; vals[35] = 0.f;
        sum += __shfl_xor(sum, 8);
        sum += __shfl_xor(sum, 16);
        sum += __shfl_xor(sum, 32);
        invv = 1.f / sum;
        if (sub == 0) invs[h * 8 + r] = invv;
    }
    __syncthreads();

    // ---- cooperative coalesced attn write: 4224 float4 = 67.6 KB contiguous ----
    {
        float* abase = attn + (size_t)(b * TSEQ + t) * (NAG * WN * NH);
        #pragma unroll 3
        for (int q4 = tid; q4 < 4224; q4 += 512) {
            const int hh = q4 & 1;
            const int rw = q4 >> 1;                    // n*264 + wm
            const int n  = rw / WN;
            const int wm = rw - n * WN;
            const int h0 = hh * 4;
            const float* pp = P + h0 * HB + n * RS + wm;
            float4 v;
            v.x = pp[0]      * invs[(h0 + 0) * 8 + n];
            v.y = pp[HB]     * invs[(h0 + 1) * 8 + n];
            v.z = pp[2 * HB] * invs[(h0 + 2) * 8 + n];
            v.w = pp[3 * HB] * invs[(h0 + 3) * 8 + n];
            *(float4*)(abase + (size_t)q4 * 4) = v;
        }
    }
    __syncthreads();   // all fp32 P reads done; bf16 alias writes may begin

    // ---- bf16 P write from registers (own head): cols [0,288) fully covered ----
    {
        const int r = lane & 7, sub = lane >> 3;
        char* brow = (char*)(P + h * HB + r * RS);
        #pragma unroll
        for (int i = 0; i < 36; ++i) {
            const int c = sub + 8 * i;                 // 0..287
            *(unsigned short*)(brow + 2 * c) = f2bf(vals[i] * invv);
        }
    }
    __builtin_amdgcn_sched_barrier(0);
    asm volatile("s_waitcnt lgkmcnt(0)" ::: "memory");
    __builtin_amdgcn_sched_barrier(0);

    // ---- PV per wave: D[8 real rows x 64], depth-2x4 prefetch on vt ----
    {
        const unsigned short* vth = vt + ((size_t)(b * 8 + h) * 64) * 2048;
        const char* arow = smem + (size_t)h * (HB * 4) + (lane & 7) * (RS * 4);

        auto vaddr = [&](int ms, int df) -> const short8* {
            int kc = key0 + ms * 32 + (lane >> 4) * 8;
            kc = (kc < 0) ? 0 : ((kc > 2040) ? 2040 : kc);
            const int d = df * 16 + (lane & 15);
            return (const short8*)(vth + (size_t)d * 2048 + kc);
        };

        short8 vf[2][4];
        #pragma unroll
        for (int df = 0; df < 4; ++df) vf[0][df] = *vaddr(0, df);
        #pragma unroll
        for (int df = 0; df < 4; ++df) vf[1][df] = *vaddr(1, df);

        f32x4 acc[4];
        #pragma unroll
        for (int df = 0; df < 4; ++df) acc[df] = (f32x4){0.f, 0.f, 0.f, 0.f};

        #pragma unroll
        for (int ms = 0; ms < 9; ++ms) {
            short8 afr = *(short8*)(arow + ms * 64 + (lane >> 4) * 16);
            #pragma unroll
            for (int df = 0; df < 4; ++df)
                acc[df] = __builtin_amdgcn_mfma_f32_16x16x32_bf16(afr, vf[ms & 1][df], acc[df], 0, 0, 0);
            if (ms + 2 < 9) {
                #pragma unroll
                for (int df = 0; df < 4; ++df) vf[ms & 1][df] = *vaddr(ms + 2, df);
            }
        }
        const int r0 = (lane >> 4) * 4;
        if (r0 < 8) {
            #pragma unroll
            for (int df = 0; df < 4; ++df) {
                const int d = df * 16 + (lane & 15);
                #pragma unroll
                for (int rg = 0; rg < 4; ++rg) {
                    const int n = r0 + rg;             // row == agent n (single t)
                    out[((size_t)(b * TSEQ + t) * NAG + n) * EE + h * HD + d] = acc[df][rg];
                }
            }
        }
    }
}

extern "C" void kernel_launch(void* const* d_in, const int* in_sizes, int n_in,
                              void* d_out, int out_size, void* d_ws, size_t ws_size,
                              hipStream_t stream) {
    const float* query = (const float*)d_in[0];
    const float* key   = (const float*)d_in[1];
    const float* value = (const float*)d_in[2];
    const unsigned char* kpm = (const unsigned char*)d_in[3];
    const float* Wq = (const float*)d_in[4];
    const float* bq = (const float*)d_in[5];
    const float* Wk = (const float*)d_in[6];
    const float* bk = (const float*)d_in[7];
    const float* Wv = (const float*)d_in[8];
    const float* bv = (const float*)d_in[9];

    float* out  = (float*)d_out;
    float* attn = out + (size_t)NBATCH * TSEQ * NAG * EE;

    unsigned short* qbf = (unsigned short*)d_ws;               // 4 MB bf16
    unsigned short* kbf = qbf + (size_t)4096 * EE;             // 4 MB
    unsigned short* vtb = kbf + (size_t)4096 * EE;             // 4 MB transposed V

    dim3 gp(32, 4, 3);
    proj_mfma_kernel<<<gp, 256, 0, stream>>>(query, key, value,
                                             Wq, Wk, Wv, bq, bk, bv,
                                             qbf, kbf, vtb);

    (void)hipFuncSetAttribute((const void*)attn_fused_kernel,
                              hipFuncAttributeMaxDynamicSharedMemorySize, SMEM2_BYTES);
    attn_fused_kernel<<<512, 512, SMEM2_BYTES, stream>>>(qbf, kbf, vtb, kpm, out, attn);
}